// Round 1
// baseline (275.868 us; speedup 1.0000x reference)
//
#include <hip/hip_runtime.h>

// PenalizedMSELoss: out = mean(w * (x - t)^2), w = 3.0 if (4.5 < x < 5.5 && t != 5) else 1.0
// x: float32[N], t: int32[N], out: float32[1]. 268 MB single-use read.
// Harness timed window also contains ~156 us of 512-MiB poison fills (rocprof
// top-5 are all fillBufferAligned @ 6.9 TB/s write) — not controllable here.
// Journal: R1 105us, R2 FAIL (reg-compaction serialized loads), R3 99us,
// R4 (asm-pin all 8 results) 252 harness / ~95 stage1 => 2.8 TB/s read.
// R5: the R4 pin forces vmcnt(0) drain each iter (asm consumes all 8 results).
//     Replace with 2-buffer software pipeline: issue B(s+1) -> consume A(s),
//     natural waitcnt is vmcnt(4), never drains. sched_barrier(0) after each
//     load batch prevents the R2 failure mode (scheduler sinking loads) without
//     creating a wait. Plain (non-nt) loads. |x-5|<0.5 via free abs modifier.
//     launch_bounds(256,8): ~56 live VGPR -> 8 waves/SIMD, all 2048 blocks
//     resident, 8 half-tiles each, zero tail imbalance at N=2^25.

#define LABEL_I   5
#define LABEL_F   5.0f
#define PENALTY_F 3.0f

typedef float vf4 __attribute__((ext_vector_type(4)));
typedef int   vi4 __attribute__((ext_vector_type(4)));

#define TPB  256
#define GRID 2048
#define HTV  512   // vf4 groups per half-tile = TPB * 2

__device__ __forceinline__ void accum4(vf4 xv, vi4 tv, float& acc) {
#pragma unroll
    for (int k = 0; k < 4; ++k) {
        float x = xv[k];
        int   t = tv[k];
        float d = x - (float)t;              // v_cvt + v_sub
        float c = x - LABEL_F;               // v_sub
        // |x-5| < 0.5  <=>  4.5 < x < 5.5 (strict, NaN-false) — abs is a free
        // VOP3 input modifier, saves one v_cmp vs two range compares.
        float w = ((__builtin_fabsf(c) < 0.5f) && (t != LABEL_I))
                      ? PENALTY_F : 1.0f;    // 2 v_cmp + s_and + v_cndmask
        acc += w * d * d;                    // v_mul + v_fmac (contracted)
    }
}

__global__ __launch_bounds__(TPB, 8) void penal_mse_stage1(
        const vf4* __restrict__ x4,
        const vi4* __restrict__ t4,
        float* __restrict__ partials,
        int n4, int nht_total, int n_tail_start, int n_total,
        const float* __restrict__ x_scalar,
        const int*  __restrict__ t_scalar) {
    const int tid = threadIdx.x;
    const int bid = blockIdx.x;

    float acc0 = 0.0f, acc1 = 0.0f;

    // Half-tiles owned by this block: bid, bid+GRID, ... (< nht_total).
    const int nht = (bid < nht_total) ? ((nht_total - bid + GRID - 1) / GRID) : 0;

    // Two named register buffers (static names — runtime-indexed arrays spill).
    vf4 xa0, xa1, xb0, xb1;
    vi4 ta0, ta1, tb0, tb1;

    // vf4 index of this thread's first element in half-tile s.
    #define HT_BASE(s) (((size_t)bid + (size_t)(s) * GRID) * HTV + (size_t)tid)

    // Issue 4 independent 16B loads; sched_barrier(0) pins them above the
    // following consume so the scheduler can't re-serialize (R2 failure mode)
    // — unlike the R4 value-pin, this forces NO waitcnt.
    #define LOAD_A(s) do { size_t _o = HT_BASE(s);                         \
        xa0 = x4[_o]; ta0 = t4[_o]; xa1 = x4[_o + TPB]; ta1 = t4[_o + TPB];\
        __builtin_amdgcn_sched_barrier(0); } while (0)
    #define LOAD_B(s) do { size_t _o = HT_BASE(s);                         \
        xb0 = x4[_o]; tb0 = t4[_o]; xb1 = x4[_o + TPB]; tb1 = t4[_o + TPB];\
        __builtin_amdgcn_sched_barrier(0); } while (0)

    #define CONSUME_A() do { accum4(xa0, ta0, acc0); accum4(xa1, ta1, acc1); } while (0)
    #define CONSUME_B() do { accum4(xb0, tb0, acc0); accum4(xb1, tb1, acc1); } while (0)

    int s = 0;
    if (nht > 0) LOAD_A(0);
    // Steady state: consuming one buffer while the other's 4 loads are in
    // flight -> compiler emits s_waitcnt vmcnt(4); outstanding never drains.
    for (; s + 2 < nht; s += 2) {
        LOAD_B(s + 1);
        CONSUME_A();
        LOAD_A(s + 2);
        CONSUME_B();
    }
    if (nht > 0) {
        if (nht - s == 2) {
            LOAD_B(s + 1);
            CONSUME_A();
            CONSUME_B();
        } else {
            CONSUME_A();
        }
    }
    float sum = acc0 + acc1;

    // Leftover vf4 groups beyond full half-tiles (empty for N = 2^25).
    for (int i = nht_total * HTV + bid * TPB + tid; i < n4; i += GRID * TPB) {
        vf4 xv = x4[i]; vi4 tv = t4[i];
        accum4(xv, tv, sum);
    }

    // Scalar tail (N % 4 != 0) — empty for N = 2^25.
    for (int j = n_tail_start + bid * TPB + tid; j < n_total; j += GRID * TPB) {
        float x = x_scalar[j];
        int   t = t_scalar[j];
        float d = x - (float)t;
        float c = x - LABEL_F;
        float w = ((__builtin_fabsf(c) < 0.5f) && (t != LABEL_I)) ? PENALTY_F : 1.0f;
        sum += w * d * d;
    }

    // Wave-64 shuffle reduction, then per-block partial to workspace.
    #pragma unroll
    for (int off = 32; off > 0; off >>= 1)
        sum += __shfl_down(sum, off, 64);

    __shared__ float wsum[4];
    int lane = threadIdx.x & 63;
    int wave = threadIdx.x >> 6;
    if (lane == 0) wsum[wave] = sum;
    __syncthreads();

    if (threadIdx.x == 0)
        partials[blockIdx.x] = (wsum[0] + wsum[1]) + (wsum[2] + wsum[3]);
}

__global__ __launch_bounds__(256) void penal_mse_stage2(
        const float* __restrict__ partials, int nparts,
        float* __restrict__ out, float inv_n) {
    float sum = 0.0f;
    for (int i = threadIdx.x; i < nparts; i += 256)
        sum += partials[i];

    #pragma unroll
    for (int off = 32; off > 0; off >>= 1)
        sum += __shfl_down(sum, off, 64);

    __shared__ float wsum[4];
    int lane = threadIdx.x & 63;
    int wave = threadIdx.x >> 6;
    if (lane == 0) wsum[wave] = sum;
    __syncthreads();

    if (threadIdx.x == 0)
        out[0] = ((wsum[0] + wsum[1]) + (wsum[2] + wsum[3])) * inv_n;
}

extern "C" void kernel_launch(void* const* d_in, const int* in_sizes, int n_in,
                              void* d_out, int out_size, void* d_ws, size_t ws_size,
                              hipStream_t stream) {
    const float* x = (const float*)d_in[0];
    const int*   t = (const int*)d_in[1];
    float* out = (float*)d_out;
    float* partials = (float*)d_ws;

    int n  = in_sizes[0];
    int n4 = n >> 2;                 // vf4 groups
    int nht_total = n4 / HTV;        // full half-tiles
    int n_tail_start = n4 << 2;
    float inv_n = 1.0f / (float)n;

    penal_mse_stage1<<<GRID, TPB, 0, stream>>>(
        (const vf4*)x, (const vi4*)t, partials,
        n4, nht_total, n_tail_start, n, x, t);

    penal_mse_stage2<<<1, TPB, 0, stream>>>(partials, GRID, out, inv_n);
}

// Round 2
// 250.862 us; speedup vs baseline: 1.0997x; 1.0997x over previous
//
#include <hip/hip_runtime.h>

// PenalizedMSELoss: out = mean(w * (x - t)^2), w = 3.0 if (4.5 < x < 5.5 && t != 5) else 1.0
// x: float32[N], t: int32[N], out: float32[1]. 268 MB single-use read.
// Harness timed window also contains ~156 us of 512-MiB poison fills
// (rocprof top-5 all fillBufferAligned @ 6.9 TB/s write) — not controllable.
// Journal:
//  R1 105us stage1 (12 VGPR). R2 FAIL (reg-compaction serialized loads).
//  R3  99us (28 VGPR) — dur invariant to L3-hit fraction.
//  R4 (asm-pin 8 loads + nt + interleave): stage1 < 78us (absent from top-5,
//     >= 3.4 TB/s), harness 252us. BEST. The pin+drain batch structure is
//     compiler-proof: all 8 loads provably in flight before the drain.
//  R5 FAILED (2-buffer pipeline + sched_barrier): allocator compacted to
//     32 VGPR, serialized loads again, stage1 104us. Lesson: occupancy is
//     not the lever (R5 had more waves, was slower); per-wave batch MLP is.
//  R6: R4 structure, batch 8 -> 16 in-flight loads per wave (256 B/thread per
//     tile), pin all 16, launch_bounds(256,4) for reg room (~90 VGPR expected).

#define LABEL_I   5
#define LABEL_F   5.0f
#define PENALTY_F 3.0f

typedef float vf4 __attribute__((ext_vector_type(4)));
typedef int   vi4 __attribute__((ext_vector_type(4)));

// Tile = 256 threads * 8 chunks = 2048 vf4 from each array (32 KB + 32 KB).
#define TILE_V 2048

__device__ __forceinline__ float term(float x, int t) {
    float d = x - (float)t;              // v_cvt + v_sub
    float c = x - LABEL_F;               // v_sub
    // |x-5| < 0.5 <=> 4.5 < x < 5.5 (exact: x-5 is Sterbenz-exact on [4,6]);
    // abs is a free VOP3 input modifier -> saves one v_cmp vs two range cmps.
    float w = ((__builtin_fabsf(c) < 0.5f) && (t != LABEL_I)) ? PENALTY_F : 1.0f;
    return w * d * d;                    // v_mul + v_fmac
}

__device__ __forceinline__ float term4(vf4 xv, vi4 tv) {
    return term(xv.x, tv.x) + term(xv.y, tv.y) + term(xv.z, tv.z) + term(xv.w, tv.w);
}

__global__ __launch_bounds__(256, 4) void penal_mse_stage1(
        const vf4* __restrict__ x4,
        const vi4* __restrict__ t4,
        float* __restrict__ partials,
        int n4, int tiles, int n_tail_start, int n_total,
        const float* __restrict__ x_scalar,
        const int*  __restrict__ t_scalar) {
    float s0 = 0.0f, s1 = 0.0f, s2 = 0.0f, s3 = 0.0f;
    float s4 = 0.0f, s5 = 0.0f, s6 = 0.0f, s7 = 0.0f;

    for (int tile = blockIdx.x; tile < tiles; tile += gridDim.x) {
        int base = tile * TILE_V + threadIdx.x;
        const vf4* xp = x4 + base;
        const vi4* tp = t4 + base;
        // 16 independent nontemporal 16 B loads (256 B/thread), interleaved
        // x/t issue order. All 16 are in flight before the pin's drain.
        vf4 a0 = __builtin_nontemporal_load(xp);
        vi4 b0 = __builtin_nontemporal_load(tp);
        vf4 a1 = __builtin_nontemporal_load(xp + 256);
        vi4 b1 = __builtin_nontemporal_load(tp + 256);
        vf4 a2 = __builtin_nontemporal_load(xp + 512);
        vi4 b2 = __builtin_nontemporal_load(tp + 512);
        vf4 a3 = __builtin_nontemporal_load(xp + 768);
        vi4 b3 = __builtin_nontemporal_load(tp + 768);
        vf4 a4 = __builtin_nontemporal_load(xp + 1024);
        vi4 b4 = __builtin_nontemporal_load(tp + 1024);
        vf4 a5 = __builtin_nontemporal_load(xp + 1280);
        vi4 b5 = __builtin_nontemporal_load(tp + 1280);
        vf4 a6 = __builtin_nontemporal_load(xp + 1536);
        vi4 b6 = __builtin_nontemporal_load(tp + 1536);
        vf4 a7 = __builtin_nontemporal_load(xp + 1792);
        vi4 b7 = __builtin_nontemporal_load(tp + 1792);
        // Pin ALL 16 results live here: register allocation cannot
        // re-serialize the loads (R2/R5 failure mode).
        asm volatile("" : "+v"(a0), "+v"(b0), "+v"(a1), "+v"(b1),
                          "+v"(a2), "+v"(b2), "+v"(a3), "+v"(b3),
                          "+v"(a4), "+v"(b4), "+v"(a5), "+v"(b5),
                          "+v"(a6), "+v"(b6), "+v"(a7), "+v"(b7));
        s0 += term4(a0, b0);
        s1 += term4(a1, b1);
        s2 += term4(a2, b2);
        s3 += term4(a3, b3);
        s4 += term4(a4, b4);
        s5 += term4(a5, b5);
        s6 += term4(a6, b6);
        s7 += term4(a7, b7);
    }

    float sum = ((s0 + s1) + (s2 + s3)) + ((s4 + s5) + (s6 + s7));

    // Leftover vf4 groups beyond full tiles (empty for N = 2^25).
    for (int i = tiles * TILE_V + blockIdx.x * blockDim.x + threadIdx.x;
         i < n4; i += gridDim.x * blockDim.x)
        sum += term4(x4[i], t4[i]);

    // Scalar tail (N % 4 != 0) — empty for N = 2^25.
    for (int j = n_tail_start + blockIdx.x * blockDim.x + threadIdx.x;
         j < n_total; j += gridDim.x * blockDim.x)
        sum += term(x_scalar[j], t_scalar[j]);

    // Wave-64 shuffle reduction, then per-block partial to workspace.
    #pragma unroll
    for (int off = 32; off > 0; off >>= 1)
        sum += __shfl_down(sum, off, 64);

    __shared__ float wsum[4];
    int lane = threadIdx.x & 63;
    int wave = threadIdx.x >> 6;
    if (lane == 0) wsum[wave] = sum;
    __syncthreads();

    if (threadIdx.x == 0)
        partials[blockIdx.x] = (wsum[0] + wsum[1]) + (wsum[2] + wsum[3]);
}

__global__ __launch_bounds__(256) void penal_mse_stage2(
        const float* __restrict__ partials, int nparts,
        float* __restrict__ out, float inv_n) {
    float sum = 0.0f;
    for (int i = threadIdx.x; i < nparts; i += 256)
        sum += partials[i];

    #pragma unroll
    for (int off = 32; off > 0; off >>= 1)
        sum += __shfl_down(sum, off, 64);

    __shared__ float wsum[4];
    int lane = threadIdx.x & 63;
    int wave = threadIdx.x >> 6;
    if (lane == 0) wsum[wave] = sum;
    __syncthreads();

    if (threadIdx.x == 0)
        out[0] = ((wsum[0] + wsum[1]) + (wsum[2] + wsum[3])) * inv_n;
}

extern "C" void kernel_launch(void* const* d_in, const int* in_sizes, int n_in,
                              void* d_out, int out_size, void* d_ws, size_t ws_size,
                              hipStream_t stream) {
    const float* x = (const float*)d_in[0];
    const int*   t = (const int*)d_in[1];
    float* out = (float*)d_out;
    float* partials = (float*)d_ws;

    int n  = in_sizes[0];
    int n4 = n >> 2;                 // vf4 groups
    int n_tail_start = n4 << 2;
    int tiles = n4 / TILE_V;         // full tiles (4096 at N = 2^25)
    float inv_n = 1.0f / (float)n;

    const int block = 256;
    const int grid = 2048;           // 2 tiles per block at N = 2^25

    penal_mse_stage1<<<grid, block, 0, stream>>>(
        (const vf4*)x, (const vi4*)t, partials,
        n4, tiles, n_tail_start, n, x, t);

    penal_mse_stage2<<<1, block, 0, stream>>>(partials, grid, out, inv_n);
}